// Round 9
// baseline (2617.068 us; speedup 1.0000x reference)
//
#include <hip/hip_runtime.h>
#include <hip/hip_bf16.h>
#include <hip/hip_cooperative_groups.h>

namespace cg = cooperative_groups;

#define NROWS 8192
#define NITER 10

typedef __attribute__((ext_vector_type(8))) short bf16x8;
typedef __attribute__((ext_vector_type(8))) unsigned short u16x8;
typedef __attribute__((ext_vector_type(16))) float f32x16;

__device__ __forceinline__ float bf2f(unsigned short u) {
  union { float f; unsigned int i; } c; c.i = ((unsigned int)u) << 16; return c.f;
}
__device__ __forceinline__ unsigned short f2bf(float f) {
  unsigned int x = __float_as_uint(f);
  unsigned int r = (x + 0x7FFFu + ((x >> 16) & 1u)) >> 16;
  return (unsigned short)r;
}

// tril inversion shared by the triangular-grid kernels
#define TRIS(b) ((b) * (257 - (b)) / 2)
__device__ __forceinline__ void tril_decode(int L, int& bi, int& bj) {
  int b = (int)((257.0f - sqrtf((float)(66049 - 8 * L))) * 0.5f);
  if (b > 127) b = 127;
  if (b < 0) b = 0;
  while (b < 127 && TRIS(b + 1) <= L) ++b;
  while (b > 0 && TRIS(b) > L) --b;
  bi = b;
  bj = b + (L - TRIS(b));
}

// fp32 -> bf16 cast, 8 elems/thread
__global__ __launch_bounds__(256) void cast_bf16(const float* __restrict__ in,
                                                 unsigned short* __restrict__ out,
                                                 int n8) {
  int idx = blockIdx.x * 256 + threadIdx.x;
  if (idx >= n8) return;
  const float4* p = (const float4*)in + (size_t)idx * 2;
  float4 a = p[0], b = p[1];
  u16x8 o;
  o[0] = f2bf(a.x); o[1] = f2bf(a.y); o[2] = f2bf(a.z); o[3] = f2bf(a.w);
  o[4] = f2bf(b.x); o[5] = f2bf(b.y); o[6] = f2bf(b.z); o[7] = f2bf(b.w);
  *(u16x8*)(out + (size_t)idx * 8) = o;
}

// C[M,NN] = A[M,K] @ B[NN,K]^T, bf16 inputs, fp32 out. 64x64 tile, 4 waves.
__global__ __launch_bounds__(256) void gemm_bt_mfma(const unsigned short* __restrict__ A,
                                                    const unsigned short* __restrict__ B,
                                                    float* __restrict__ C,
                                                    int NN, int K) {
  __shared__ __align__(16) unsigned short Asw[4096];
  __shared__ __align__(16) unsigned short Bsw[4096];
  const int i0 = blockIdx.x * 64, j0 = blockIdx.y * 64;
  const int t = threadIdx.x;
  const int lane = t & 63;
  const int wv = t >> 6;
  const int wi = wv >> 1, wj = wv & 1;
  const int khalf = lane >> 5;

  f32x16 acc;
#pragma unroll
  for (int r = 0; r < 16; ++r) acc[r] = 0.f;

  const int lrow = t >> 2;
  const int lgp = (t & 3) * 2;
  const int arow = wi * 32 + (lane & 31);
  const int brow = wj * 32 + (lane & 31);
  const int nc = K >> 6;
#pragma unroll 1
  for (int c = 0; c < nc; ++c) {
    const unsigned short* sa = A + (size_t)(i0 + lrow) * K + c * 64 + lgp * 8;
    const unsigned short* sb = B + (size_t)(j0 + lrow) * K + c * 64 + lgp * 8;
    u16x8 va0 = *(const u16x8*)(sa);
    u16x8 va1 = *(const u16x8*)(sa + 8);
    u16x8 vb0 = *(const u16x8*)(sb);
    u16x8 vb1 = *(const u16x8*)(sb + 8);
    __syncthreads();
    int s0 = (lgp ^ (lrow & 7)) * 8;
    int s1 = ((lgp + 1) ^ (lrow & 7)) * 8;
    *(u16x8*)&Asw[lrow * 64 + s0] = va0;
    *(u16x8*)&Asw[lrow * 64 + s1] = va1;
    *(u16x8*)&Bsw[lrow * 64 + s0] = vb0;
    *(u16x8*)&Bsw[lrow * 64 + s1] = vb1;
    __syncthreads();
#pragma unroll
    for (int s = 0; s < 4; ++s) {
      int slot = s * 2 + khalf;
      bf16x8 a = *(const bf16x8*)&Asw[arow * 64 + ((slot ^ (arow & 7)) * 8)];
      bf16x8 b = *(const bf16x8*)&Bsw[brow * 64 + ((slot ^ (brow & 7)) * 8)];
      acc = __builtin_amdgcn_mfma_f32_32x32x16_bf16(a, b, acc, 0, 0, 0);
    }
  }
#pragma unroll
  for (int r = 0; r < 16; ++r) {
    int rowl = (r & 3) + 8 * (r >> 2) + 4 * khalf;
    int coll = lane & 31;
    C[(size_t)(i0 + wi * 32 + rowl) * NN + j0 + wj * 32 + coll] = acc[r];
  }
}

// per-column partial sums (deterministic two-stage BN stats)
__global__ __launch_bounds__(256) void colstats(const float* __restrict__ in, int C,
                                                float* __restrict__ pS,
                                                float* __restrict__ pSS) {
  const int t = threadIdx.x;
  const int col = blockIdx.x * 64 + (t & 63);
  const int rp = t >> 6;
  const int r0 = blockIdx.y * 128;
  float s = 0.f, ss = 0.f;
  for (int r = rp; r < 128; r += 4) {
    float v = in[(size_t)(r0 + r) * C + col];
    s += v; ss += v * v;
  }
  __shared__ float lS[4][64], lQ[4][64];
  lS[rp][t & 63] = s; lQ[rp][t & 63] = ss;
  __syncthreads();
  if (t < 64) {
    float ts = lS[0][t] + lS[1][t] + lS[2][t] + lS[3][t];
    float tq = lQ[0][t] + lQ[1][t] + lQ[2][t] + lQ[3][t];
    pS[(size_t)blockIdx.y * C + blockIdx.x * 64 + t] = ts;
    pSS[(size_t)blockIdx.y * C + blockIdx.x * 64 + t] = tq;
  }
}

__global__ void bn_finalize(const float* __restrict__ pS, const float* __restrict__ pSS,
                            const float* __restrict__ g, const float* __restrict__ be,
                            float2* __restrict__ ab, int C) {
  int c = blockIdx.x * 256 + threadIdx.x;
  if (c >= C) return;
  float s = 0.f, q = 0.f;
  for (int r = 0; r < 64; ++r) { s += pS[r * C + c]; q += pSS[r * C + c]; }
  const float invM = 1.f / 8192.f;
  float mu = s * invM;
  float var = q * invM - mu * mu;
  float rstd = rsqrtf(var + 1e-5f);
  float a = g[c] * rstd;
  ab[c] = make_float2(a, be[c] - mu * a);
}

// layer-1: hb(bf16) = leaky_relu(a*h + b)
__global__ __launch_bounds__(256) void bn_act_h2b(const float* __restrict__ h,
                                                  const float2* __restrict__ ab,
                                                  unsigned short* __restrict__ hb,
                                                  int Cmask) {
  size_t idx = (size_t)blockIdx.x * 256 + threadIdx.x;
  float4 v = ((const float4*)h)[idx];
  int cb = (int)((idx * 4) & (size_t)Cmask);
  float2 a0 = ab[cb], a1 = ab[cb + 1], a2 = ab[cb + 2], a3 = ab[cb + 3];
  float r0 = a0.x * v.x + a0.y; r0 = r0 >= 0.f ? r0 : 0.01f * r0;
  float r1 = a1.x * v.y + a1.y; r1 = r1 >= 0.f ? r1 : 0.01f * r1;
  float r2 = a2.x * v.z + a2.y; r2 = r2 >= 0.f ? r2 : 0.01f * r2;
  float r3 = a3.x * v.w + a3.y; r3 = r3 >= 0.f ? r3 : 0.01f * r3;
  *(ushort4*)(hb + idx * 4) = make_ushort4(f2bf(r0), f2bf(r1), f2bf(r2), f2bf(r3));
}

// in-place: h = leaky_relu(a*h + b), per column (fp32)
__global__ __launch_bounds__(256) void bn_act(float* __restrict__ h,
                                              const float2* __restrict__ ab,
                                              int Cmask) {
  size_t idx = (size_t)blockIdx.x * 256 + threadIdx.x;
  float4 v = ((const float4*)h)[idx];
  int cb = (int)((idx * 4) & (size_t)Cmask);
  float2 a0 = ab[cb], a1 = ab[cb + 1], a2 = ab[cb + 2], a3 = ab[cb + 3];
  float r0 = a0.x * v.x + a0.y; r0 = r0 >= 0.f ? r0 : 0.01f * r0;
  float r1 = a1.x * v.y + a1.y; r1 = r1 >= 0.f ? r1 : 0.01f * r1;
  float r2 = a2.x * v.z + a2.y; r2 = r2 >= 0.f ? r2 : 0.01f * r2;
  float r3 = a3.x * v.w + a3.y; r3 = r3 >= 0.f ? r3 : 0.01f * r3;
  ((float4*)h)[idx] = make_float4(r0, r1, r2, r3);
}

// per row: fn, unary logit, coef0; write row-normalized feats as bf16
__global__ __launch_bounds__(256) void rowfn(const float* __restrict__ feats,
                                             const float* __restrict__ fcw,
                                             const float* __restrict__ fcb,
                                             unsigned short* __restrict__ fnorm,
                                             float* __restrict__ unary,
                                             float* __restrict__ coef0) {
  const int lane = threadIdx.x & 63;
  const int row = blockIdx.x * 4 + (threadIdx.x >> 6);
  const float* fr = feats + (size_t)row * 256;
  float4 v = *(const float4*)(fr + lane * 4);
  float4 w = *(const float4*)(fcw + lane * 4);
  float ssq = v.x * v.x + v.y * v.y + v.z * v.z + v.w * v.w;
  float dot = v.x * w.x + v.y * w.y + v.z * w.z + v.w * w.w;
#pragma unroll
  for (int o = 32; o; o >>= 1) { ssq += __shfl_xor(ssq, o); dot += __shfl_xor(dot, o); }
  float rfn = rsqrtf(ssq);
  *(ushort4*)(fnorm + (size_t)row * 256 + lane * 4) =
      make_ushort4(f2bf(v.x * rfn), f2bf(v.y * rfn), f2bf(v.z * rfn), f2bf(v.w * rfn));
  if (lane == 0) {
    float lg = dot + fcb[0];
    unary[row] = lg;
    coef0[row] = 1.f - 2.f / (1.f + __expf(-lg));
  }
}

// PP[i,j] = (fnorm_i . fnorm_j) * 0.5*(W[i,j]+W[j,i])  stored bf16
// Triangular grid; ONLY the upper-triangle tile is written (no mirror).
__global__ __launch_bounds__(256) void ppbuild_sym(const unsigned short* __restrict__ fnorm,
                                                   const float* __restrict__ W,
                                                   unsigned short* __restrict__ PP) {
  int bi, bj;
  tril_decode(blockIdx.x, bi, bj);
  const int i0 = bi * 64, j0 = bj * 64;

  __shared__ __align__(16) unsigned char shm[18944];
  unsigned short* Asw = (unsigned short*)shm;
  unsigned short* Bsw = (unsigned short*)shm + 4736;
  float (*Wt)[68] = (float(*)[68])shm;
  unsigned short* OutD = (unsigned short*)shm;

  const int t = threadIdx.x;
  const int lane = t & 63;
  const int wv = t >> 6;
  const int wi = wv >> 1, wj = wv & 1;
  const int khalf = lane >> 5;

  f32x16 acc;
#pragma unroll
  for (int r = 0; r < 16; ++r) acc[r] = 0.f;

  const int lrow = t >> 2;
  const int lgp = (t & 3) * 2;
  const int arow = wi * 32 + (lane & 31);
  const int brow = wj * 32 + (lane & 31);
#pragma unroll 1
  for (int c = 0; c < 4; ++c) {
    const unsigned short* sa = fnorm + (size_t)(i0 + lrow) * 256 + c * 64 + lgp * 8;
    const unsigned short* sb = fnorm + (size_t)(j0 + lrow) * 256 + c * 64 + lgp * 8;
    u16x8 va0 = *(const u16x8*)(sa);
    u16x8 va1 = *(const u16x8*)(sa + 8);
    u16x8 vb0 = *(const u16x8*)(sb);
    u16x8 vb1 = *(const u16x8*)(sb + 8);
    __syncthreads();
    int s0 = (lgp ^ (lrow & 7)) * 8;
    int s1 = ((lgp + 1) ^ (lrow & 7)) * 8;
    *(u16x8*)&Asw[lrow * 64 + s0] = va0;
    *(u16x8*)&Asw[lrow * 64 + s1] = va1;
    *(u16x8*)&Bsw[lrow * 64 + s0] = vb0;
    *(u16x8*)&Bsw[lrow * 64 + s1] = vb1;
    __syncthreads();
#pragma unroll
    for (int s = 0; s < 4; ++s) {
      int slot = s * 2 + khalf;
      bf16x8 a = *(const bf16x8*)&Asw[arow * 64 + ((slot ^ (arow & 7)) * 8)];
      bf16x8 b = *(const bf16x8*)&Bsw[brow * 64 + ((slot ^ (brow & 7)) * 8)];
      acc = __builtin_amdgcn_mfma_f32_32x32x16_bf16(a, b, acc, 0, 0, 0);
    }
  }

  __syncthreads();
  {
    const int j = t >> 2, cb = (t & 3) * 16;
    const float* src = W + (size_t)(j0 + j) * NROWS + i0 + cb;
#pragma unroll
    for (int q = 0; q < 4; ++q) {
      float4 v = *(const float4*)(src + q * 4);
      Wt[j][cb + q * 4 + 0] = v.x; Wt[j][cb + q * 4 + 1] = v.y;
      Wt[j][cb + q * 4 + 2] = v.z; Wt[j][cb + q * 4 + 3] = v.w;
    }
  }
  __syncthreads();
  unsigned short pb[16];
#pragma unroll
  for (int r = 0; r < 16; ++r) {
    int rowl = (r & 3) + 8 * (r >> 2) + 4 * khalf;
    int coll = lane & 31;
    int il = wi * 32 + rowl, jl = wj * 32 + coll;
    float wd = W[(size_t)(i0 + il) * NROWS + (j0 + jl)];
    float ws = 0.5f * (wd + Wt[jl][il]);
    pb[r] = f2bf(acc[r] * ws);
  }
  __syncthreads();
#pragma unroll
  for (int r = 0; r < 16; ++r) {
    int rowl = (r & 3) + 8 * (r >> 2) + 4 * khalf;
    int coll = lane & 31;
    OutD[(wi * 32 + rowl) * 74 + wj * 32 + coll] = pb[r];
  }
  __syncthreads();
  const int row = t >> 3;
  const int seg = t & 7;
#pragma unroll
  for (int q = 0; q < 2; ++q) {
    int rr = row + q * 32;
    const unsigned int* pd = (const unsigned int*)(OutD + rr * 74 + seg * 8);
    union { u16x8 v; unsigned int u[4]; } dd;
#pragma unroll
    for (int k = 0; k < 4; ++k) dd.u[k] = pd[k];
    *(u16x8*)(PP + (size_t)(i0 + rr) * NROWS + j0 + seg * 8) = dd.v;
  }
}

// ---------- persistent cooperative iteration kernel ----------
// 10 iterations of: symmetric tile matvec partials -> grid.sync ->
// fold 128 slots + sigmoid -> grid.sync. One launch total.
__global__ __launch_bounds__(256, 4) void ppiter_persist(
    const unsigned short* __restrict__ PP,
    const float* __restrict__ unary,
    float* __restrict__ coefA,
    float* __restrict__ coefB,
    float* __restrict__ pE,
    float* __restrict__ out) {
  cg::grid_group grid = cg::this_grid();
  const int t = threadIdx.x;
  __shared__ unsigned short tile[64][68];
  __shared__ float cj[64], ci[64], Tw[4][64], Dred[64];

  const int r = t >> 2, c0 = (t & 3) * 16;
  const int cT = t & 63, wT = t >> 6;

  for (int it = 0; it < NITER; ++it) {
    const float* cin = (it & 1) ? coefB : coefA;
    float* cout = (it & 1) ? coefA : coefB;
    for (int L = blockIdx.x; L < 8256; L += gridDim.x) {
      int bi, bj;
      tril_decode(L, bi, bj);
      const int i0 = bi * 64, j0 = bj * 64;
      __syncthreads();   // protect LDS reuse across tiles/iterations
      if (t < 64) cj[t] = cin[j0 + t];
      else if (t < 128) ci[t - 64] = cin[i0 + (t - 64)];
      const unsigned short* src = PP + (size_t)(i0 + r) * NROWS + j0 + c0;
      u16x8 v0 = *(const u16x8*)(src);
      u16x8 v1 = *(const u16x8*)(src + 8);
      *(u16x8*)&tile[r][c0] = v0;
      *(u16x8*)&tile[r][c0 + 8] = v1;
      __syncthreads();
      // direct row sums (4 lanes per row)
      {
        float a = 0.f;
#pragma unroll
        for (int k = 0; k < 16; ++k) a += bf2f(tile[r][c0 + k]) * cj[c0 + k];
        a += __shfl_xor(a, 1);
        a += __shfl_xor(a, 2);
        if ((t & 3) == 0) Dred[r] = a;
      }
      // transposed column sums (per-wave row stripe)
      {
        float a = 0.f;
#pragma unroll
        for (int k = 0; k < 16; ++k) a += bf2f(tile[wT * 16 + k][cT]) * ci[wT * 16 + k];
        Tw[wT][cT] = a;
      }
      __syncthreads();
      if (t < 64) {
        pE[(size_t)bj * NROWS + i0 + t] = Dred[t];
        if (bi != bj) {
          float s = (Tw[0][t] + Tw[1][t]) + (Tw[2][t] + Tw[3][t]);
          pE[(size_t)bi * NROWS + j0 + t] = s;
        }
      }
    }
    grid.sync();
    {
      int gid = blockIdx.x * 256 + t;
      if (gid < NROWS) {
        float acc = 0.f;
#pragma unroll 8
        for (int s = 0; s < 128; ++s) acc += pE[(size_t)s * NROWS + gid];
        float lg = unary[gid] + acc;
        cout[gid] = 1.f - 2.f / (1.f + __expf(-lg));
        if (it == NITER - 1) out[gid] = lg;
      }
    }
    grid.sync();
  }
}

// ---------- fallback (round-7) iteration kernels ----------
__global__ __launch_bounds__(256) void ppmv_sym(const unsigned short* __restrict__ PP,
                                                const float* __restrict__ coef_in,
                                                float* __restrict__ pE) {
  int bi, bj;
  tril_decode(blockIdx.x, bi, bj);
  const int i0 = bi * 64, j0 = bj * 64;
  const int t = threadIdx.x;

  __shared__ unsigned short tile[64][68];
  __shared__ float cj[64], ci[64], Tw[4][64], Dred[64];
  if (t < 64) cj[t] = coef_in[j0 + t];
  else if (t < 128) ci[t - 64] = coef_in[i0 + (t - 64)];
  {
    int r = t >> 2, c0 = (t & 3) * 16;
    const unsigned short* src = PP + (size_t)(i0 + r) * NROWS + j0 + c0;
    u16x8 v0 = *(const u16x8*)(src);
    u16x8 v1 = *(const u16x8*)(src + 8);
    *(u16x8*)&tile[r][c0] = v0;
    *(u16x8*)&tile[r][c0 + 8] = v1;
  }
  __syncthreads();
  {
    int r = t >> 2, c0 = (t & 3) * 16;
    float a = 0.f;
#pragma unroll
    for (int k = 0; k < 16; ++k) a += bf2f(tile[r][c0 + k]) * cj[c0 + k];
    a += __shfl_xor(a, 1);
    a += __shfl_xor(a, 2);
    if ((t & 3) == 0) Dred[r] = a;
  }
  {
    int c = t & 63, w = t >> 6;
    float a = 0.f;
#pragma unroll
    for (int k = 0; k < 16; ++k) a += bf2f(tile[w * 16 + k][c]) * ci[w * 16 + k];
    Tw[w][c] = a;
  }
  __syncthreads();
  if (t < 64) {
    pE[(size_t)bj * NROWS + i0 + t] = Dred[t];
    if (bi != bj) {
      float s = (Tw[0][t] + Tw[1][t]) + (Tw[2][t] + Tw[3][t]);
      pE[(size_t)bi * NROWS + j0 + t] = s;
    }
  }
}

__global__ __launch_bounds__(256) void ppmv_reduce(const float* __restrict__ pE,
                                                   const float* __restrict__ unary,
                                                   float* __restrict__ coef_out,
                                                   float* __restrict__ lg_out) {
  int row = blockIdx.x * 256 + threadIdx.x;
  float acc = 0.f;
#pragma unroll 8
  for (int s = 0; s < 128; ++s) acc += pE[(size_t)s * NROWS + row];
  float lg = unary[row] + acc;
  coef_out[row] = 1.f - 2.f / (1.f + __expf(-lg));
  if (lg_out) lg_out[row] = lg;
}

extern "C" void kernel_launch(void* const* d_in, const int* in_sizes, int n_in,
                              void* d_out, int out_size, void* d_ws, size_t ws_size,
                              hipStream_t stream) {
  const float* x   = (const float*)d_in[0];
  const float* W   = (const float*)d_in[1];
  const float* W1  = (const float*)d_in[2];
  const float* g1  = (const float*)d_in[4];
  const float* be1 = (const float*)d_in[5];
  const float* W2  = (const float*)d_in[6];
  const float* g2  = (const float*)d_in[8];
  const float* be2 = (const float*)d_in[9];
  const float* fcw = (const float*)d_in[10];
  const float* fcb = (const float*)d_in[11];
  float* out = (float*)d_out;

  char* ws = (char*)d_ws;
  float* h      = (float*)(ws + 0);              // 16 MB (reused as pE later)
  float* pE     = h;                             // [128][8192] fp32 = 4 MB
  float* feats  = (float*)(ws + 16777216);       // 8 MB
  float* p1s    = (float*)(ws + 25165824);
  float* p1q    = (float*)(ws + 25296896);
  float* p2s    = (float*)(ws + 25427968);
  float* p2q    = (float*)(ws + 25493504);
  float2* ab1   = (float2*)(ws + 25559040);
  float2* ab2   = (float2*)(ws + 25563136);
  unsigned short* fnorm = (unsigned short*)(ws + 25565184);  // 4 MB
  float* unary  = (float*)(ws + 29759488);
  float* coefA  = (float*)(ws + 29792256);
  float* coefB  = (float*)(ws + 29825024);
  unsigned short* PP  = (unsigned short*)(ws + 29857792);    // 128 MB
  unsigned short* xb  = (unsigned short*)(ws + 164075520);   // 2 MB
  unsigned short* w1b = (unsigned short*)(ws + 166172672);
  unsigned short* w2b = (unsigned short*)(ws + 166303744);
  unsigned short* hb  = (unsigned short*)(ws + 166565888);   // 8 MB
  if (ws_size < (size_t)174954496) return;

  // bf16 casts of MLP inputs/weights
  cast_bf16<<<512, 256, 0, stream>>>(x, xb, 131072);
  cast_bf16<<<32, 256, 0, stream>>>(W1, w1b, 8192);
  cast_bf16<<<64, 256, 0, stream>>>(W2, w2b, 16384);
  // layer 1: h = x @ W1^T (MFMA) ; BN ; leaky -> hb (bf16)
  gemm_bt_mfma<<<dim3(128, 8), 256, 0, stream>>>(xb, w1b, h, 512, 128);
  colstats<<<dim3(8, 64), 256, 0, stream>>>(h, 512, p1s, p1q);
  bn_finalize<<<2, 256, 0, stream>>>(p1s, p1q, g1, be1, ab1, 512);
  bn_act_h2b<<<4096, 256, 0, stream>>>(h, ab1, hb, 511);
  // layer 2: feats = hb @ W2^T (MFMA) ; BN ; leaky
  gemm_bt_mfma<<<dim3(128, 4), 256, 0, stream>>>(hb, w2b, feats, 256, 512);
  colstats<<<dim3(4, 64), 256, 0, stream>>>(feats, 256, p2s, p2q);
  bn_finalize<<<1, 256, 0, stream>>>(p2s, p2q, g2, be2, ab2, 256);
  bn_act<<<2048, 256, 0, stream>>>(feats, ab2, 255);
  // row norms + unary logits + coef0
  rowfn<<<2048, 256, 0, stream>>>(feats, fcw, fcb, fnorm, unary, coefA);
  // PP upper triangle (h is dead from here; pE aliases it)
  ppbuild_sym<<<8256, 256, 0, stream>>>(fnorm, W, PP);
  // 10 iterations in ONE cooperative launch (fallback: per-iter kernels)
  {
    void* args[] = {(void*)&PP, (void*)&unary, (void*)&coefA, (void*)&coefB,
                    (void*)&pE, (void*)&out};
    hipError_t e = hipLaunchCooperativeKernel((void*)ppiter_persist,
                                              dim3(1024), dim3(256), args, 0, stream);
    if (e != hipSuccess) {
      float* cur = coefA; float* nxt = coefB;
      for (int it = 0; it < NITER; ++it) {
        ppmv_sym<<<8256, 256, 0, stream>>>(PP, cur, pE);
        ppmv_reduce<<<32, 256, 0, stream>>>(pE, unary, nxt,
                                            it == NITER - 1 ? out : nullptr);
        float* tmp = cur; cur = nxt; nxt = tmp;
      }
    }
  }
}

// Round 10
// 339.521 us; speedup vs baseline: 7.7081x; 7.7081x over previous
//
#include <hip/hip_runtime.h>
#include <hip/hip_bf16.h>

#define NROWS 8192
#define NITER 10

typedef __attribute__((ext_vector_type(8))) short bf16x8;
typedef __attribute__((ext_vector_type(8))) unsigned short u16x8;
typedef __attribute__((ext_vector_type(16))) float f32x16;

__device__ __forceinline__ float bf2f(unsigned short u) {
  union { float f; unsigned int i; } c; c.i = ((unsigned int)u) << 16; return c.f;
}
__device__ __forceinline__ unsigned short f2bf(float f) {
  unsigned int x = __float_as_uint(f);
  unsigned int r = (x + 0x7FFFu + ((x >> 16) & 1u)) >> 16;
  return (unsigned short)r;
}

// tril inversion for triangular-grid kernels
#define TRIS(b) ((b) * (257 - (b)) / 2)
__device__ __forceinline__ void tril_decode(int L, int& bi, int& bj) {
  int b = (int)((257.0f - sqrtf((float)(66049 - 8 * L))) * 0.5f);
  if (b > 127) b = 127;
  if (b < 0) b = 0;
  while (b < 127 && TRIS(b + 1) <= L) ++b;
  while (b > 0 && TRIS(b) > L) --b;
  bi = b;
  bj = b + (L - TRIS(b));
}

// one kernel casting x, W1, W2 to bf16 (8 elems/thread)
__global__ __launch_bounds__(256) void cast3(const float* __restrict__ x,
                                             const float* __restrict__ W1,
                                             const float* __restrict__ W2,
                                             unsigned short* __restrict__ xb,
                                             unsigned short* __restrict__ w1b,
                                             unsigned short* __restrict__ w2b) {
  int idx = blockIdx.x * 256 + threadIdx.x;
  const float* src; unsigned short* dst; int l;
  if (idx < 131072) { src = x; dst = xb; l = idx; }
  else if (idx < 139264) { src = W1; dst = w1b; l = idx - 131072; }
  else if (idx < 155648) { src = W2; dst = w2b; l = idx - 139264; }
  else return;
  const float4* p = (const float4*)src + (size_t)l * 2;
  float4 a = p[0], b = p[1];
  u16x8 o;
  o[0] = f2bf(a.x); o[1] = f2bf(a.y); o[2] = f2bf(a.z); o[3] = f2bf(a.w);
  o[4] = f2bf(b.x); o[5] = f2bf(b.y); o[6] = f2bf(b.z); o[7] = f2bf(b.w);
  *(u16x8*)(dst + (size_t)l * 8) = o;
}

// C[M,NN] = A[M,K] @ B[NN,K]^T (bf16 in, bf16 out) + fused per-column
// partial BN stats (sum, sumsq) from the fp32 accumulators.
__global__ __launch_bounds__(256) void gemm_bt_mfma_stats(
    const unsigned short* __restrict__ A, const unsigned short* __restrict__ B,
    unsigned short* __restrict__ Cb, float* __restrict__ pS, float* __restrict__ pQ,
    int NN, int K) {
  __shared__ __align__(16) unsigned short Asw[4096];
  __shared__ __align__(16) unsigned short Bsw[4096];
  __shared__ float Sarr[4][64], Qarr[4][64];
  const int i0 = blockIdx.x * 64, j0 = blockIdx.y * 64;
  const int t = threadIdx.x;
  const int lane = t & 63;
  const int wv = t >> 6;
  const int wi = wv >> 1, wj = wv & 1;
  const int khalf = lane >> 5;

  f32x16 acc;
#pragma unroll
  for (int r = 0; r < 16; ++r) acc[r] = 0.f;

  const int lrow = t >> 2;
  const int lgp = (t & 3) * 2;
  const int arow = wi * 32 + (lane & 31);
  const int brow = wj * 32 + (lane & 31);
  const int nc = K >> 6;
#pragma unroll 1
  for (int c = 0; c < nc; ++c) {
    const unsigned short* sa = A + (size_t)(i0 + lrow) * K + c * 64 + lgp * 8;
    const unsigned short* sb = B + (size_t)(j0 + lrow) * K + c * 64 + lgp * 8;
    u16x8 va0 = *(const u16x8*)(sa);
    u16x8 va1 = *(const u16x8*)(sa + 8);
    u16x8 vb0 = *(const u16x8*)(sb);
    u16x8 vb1 = *(const u16x8*)(sb + 8);
    __syncthreads();
    int s0 = (lgp ^ (lrow & 7)) * 8;
    int s1 = ((lgp + 1) ^ (lrow & 7)) * 8;
    *(u16x8*)&Asw[lrow * 64 + s0] = va0;
    *(u16x8*)&Asw[lrow * 64 + s1] = va1;
    *(u16x8*)&Bsw[lrow * 64 + s0] = vb0;
    *(u16x8*)&Bsw[lrow * 64 + s1] = vb1;
    __syncthreads();
#pragma unroll
    for (int s = 0; s < 4; ++s) {
      int slot = s * 2 + khalf;
      bf16x8 a = *(const bf16x8*)&Asw[arow * 64 + ((slot ^ (arow & 7)) * 8)];
      bf16x8 b = *(const bf16x8*)&Bsw[brow * 64 + ((slot ^ (brow & 7)) * 8)];
      acc = __builtin_amdgcn_mfma_f32_32x32x16_bf16(a, b, acc, 0, 0, 0);
    }
  }
  // epilogue: bf16 store + per-lane column stats (16 rows of column coll)
  float s = 0.f, q = 0.f;
#pragma unroll
  for (int r = 0; r < 16; ++r) {
    int rowl = (r & 3) + 8 * (r >> 2) + 4 * khalf;
    int coll = lane & 31;
    float v = acc[r];
    s += v; q += v * v;
    Cb[(size_t)(i0 + wi * 32 + rowl) * NN + j0 + wj * 32 + coll] = f2bf(v);
  }
  Sarr[wv][lane] = s;
  Qarr[wv][lane] = q;
  __syncthreads();
  if (t < 64) {  // column c of block: fold 4 deterministic contributions
    int wjc = t >> 5, coll = t & 31;
    float st = (Sarr[wjc][coll] + Sarr[wjc][coll + 32]) +
               (Sarr[wjc + 2][coll] + Sarr[wjc + 2][coll + 32]);
    float qt = (Qarr[wjc][coll] + Qarr[wjc][coll + 32]) +
               (Qarr[wjc + 2][coll] + Qarr[wjc + 2][coll + 32]);
    pS[(size_t)blockIdx.x * NN + j0 + t] = st;
    pQ[(size_t)blockIdx.x * NN + j0 + t] = qt;
  }
}

// fold 128 row-block partial stats -> per-column scale/shift
__global__ void bn_finalize(const float* __restrict__ pS, const float* __restrict__ pQ,
                            const float* __restrict__ g, const float* __restrict__ be,
                            float2* __restrict__ ab, int C) {
  int c = blockIdx.x * 256 + threadIdx.x;
  if (c >= C) return;
  float s = 0.f, q = 0.f;
  for (int r = 0; r < 128; ++r) { s += pS[(size_t)r * C + c]; q += pQ[(size_t)r * C + c]; }
  const float invM = 1.f / 8192.f;
  float mu = s * invM;
  float var = q * invM - mu * mu;
  float rstd = rsqrtf(var + 1e-5f);
  float a = g[c] * rstd;
  ab[c] = make_float2(a, be[c] - mu * a);
}

// hb = leaky_relu(a*hraw + b), bf16 -> bf16, 8 elems/thread
__global__ __launch_bounds__(256) void bn_apply(const unsigned short* __restrict__ hraw,
                                                const float2* __restrict__ ab,
                                                unsigned short* __restrict__ hb,
                                                int Cmask) {
  size_t idx = (size_t)blockIdx.x * 256 + threadIdx.x;
  u16x8 v = *(const u16x8*)(hraw + idx * 8);
  int cb = (int)((idx * 8) & (size_t)Cmask);
  u16x8 o;
#pragma unroll
  for (int k = 0; k < 8; ++k) {
    float2 a = ab[cb + k];
    float r = a.x * bf2f(v[k]) + a.y;
    r = r >= 0.f ? r : 0.01f * r;
    o[k] = f2bf(r);
  }
  *(u16x8*)(hb + idx * 8) = o;
}

// fused: feats-BN + leaky + row norm + fc logit; writes fnorm bf16, unary, coef0
__global__ __launch_bounds__(256) void bn_rowfn(const unsigned short* __restrict__ fraw,
                                                const float2* __restrict__ ab,
                                                const float* __restrict__ fcw,
                                                const float* __restrict__ fcb,
                                                unsigned short* __restrict__ fnorm,
                                                float* __restrict__ unary,
                                                float* __restrict__ coef0) {
  const int lane = threadIdx.x & 63;
  const int row = blockIdx.x * 4 + (threadIdx.x >> 6);
  ushort4 v4 = *(const ushort4*)(fraw + (size_t)row * 256 + lane * 4);
  float4 w = *(const float4*)(fcw + lane * 4);
  int c = lane * 4;
  float2 a0 = ab[c], a1 = ab[c + 1], a2 = ab[c + 2], a3 = ab[c + 3];
  float f0 = a0.x * bf2f(v4.x) + a0.y; f0 = f0 >= 0.f ? f0 : 0.01f * f0;
  float f1 = a1.x * bf2f(v4.y) + a1.y; f1 = f1 >= 0.f ? f1 : 0.01f * f1;
  float f2 = a2.x * bf2f(v4.z) + a2.y; f2 = f2 >= 0.f ? f2 : 0.01f * f2;
  float f3 = a3.x * bf2f(v4.w) + a3.y; f3 = f3 >= 0.f ? f3 : 0.01f * f3;
  float ssq = f0 * f0 + f1 * f1 + f2 * f2 + f3 * f3;
  float dot = f0 * w.x + f1 * w.y + f2 * w.z + f3 * w.w;
#pragma unroll
  for (int o = 32; o; o >>= 1) { ssq += __shfl_xor(ssq, o); dot += __shfl_xor(dot, o); }
  float rfn = rsqrtf(ssq);
  *(ushort4*)(fnorm + (size_t)row * 256 + lane * 4) =
      make_ushort4(f2bf(f0 * rfn), f2bf(f1 * rfn), f2bf(f2 * rfn), f2bf(f3 * rfn));
  if (lane == 0) {
    float lg = dot + fcb[0];
    unary[row] = lg;
    coef0[row] = 1.f - 2.f / (1.f + __expf(-lg));
  }
}

// PP[i,j] = (fnorm_i . fnorm_j) * 0.5*(W[i,j]+W[j,i]); upper-triangle only.
__global__ __launch_bounds__(256) void ppbuild_sym(const unsigned short* __restrict__ fnorm,
                                                   const float* __restrict__ W,
                                                   unsigned short* __restrict__ PP) {
  int bi, bj;
  tril_decode(blockIdx.x, bi, bj);
  const int i0 = bi * 64, j0 = bj * 64;

  __shared__ __align__(16) unsigned char shm[18944];
  unsigned short* Asw = (unsigned short*)shm;
  unsigned short* Bsw = (unsigned short*)shm + 4736;
  float (*Wt)[68] = (float(*)[68])shm;
  unsigned short* OutD = (unsigned short*)shm;

  const int t = threadIdx.x;
  const int lane = t & 63;
  const int wv = t >> 6;
  const int wi = wv >> 1, wj = wv & 1;
  const int khalf = lane >> 5;

  f32x16 acc;
#pragma unroll
  for (int r = 0; r < 16; ++r) acc[r] = 0.f;

  const int lrow = t >> 2;
  const int lgp = (t & 3) * 2;
  const int arow = wi * 32 + (lane & 31);
  const int brow = wj * 32 + (lane & 31);
#pragma unroll 1
  for (int c = 0; c < 4; ++c) {
    const unsigned short* sa = fnorm + (size_t)(i0 + lrow) * 256 + c * 64 + lgp * 8;
    const unsigned short* sb = fnorm + (size_t)(j0 + lrow) * 256 + c * 64 + lgp * 8;
    u16x8 va0 = *(const u16x8*)(sa);
    u16x8 va1 = *(const u16x8*)(sa + 8);
    u16x8 vb0 = *(const u16x8*)(sb);
    u16x8 vb1 = *(const u16x8*)(sb + 8);
    __syncthreads();
    int s0 = (lgp ^ (lrow & 7)) * 8;
    int s1 = ((lgp + 1) ^ (lrow & 7)) * 8;
    *(u16x8*)&Asw[lrow * 64 + s0] = va0;
    *(u16x8*)&Asw[lrow * 64 + s1] = va1;
    *(u16x8*)&Bsw[lrow * 64 + s0] = vb0;
    *(u16x8*)&Bsw[lrow * 64 + s1] = vb1;
    __syncthreads();
#pragma unroll
    for (int s = 0; s < 4; ++s) {
      int slot = s * 2 + khalf;
      bf16x8 a = *(const bf16x8*)&Asw[arow * 64 + ((slot ^ (arow & 7)) * 8)];
      bf16x8 b = *(const bf16x8*)&Bsw[brow * 64 + ((slot ^ (brow & 7)) * 8)];
      acc = __builtin_amdgcn_mfma_f32_32x32x16_bf16(a, b, acc, 0, 0, 0);
    }
  }

  __syncthreads();
  {
    const int j = t >> 2, cb = (t & 3) * 16;
    const float* src = W + (size_t)(j0 + j) * NROWS + i0 + cb;
#pragma unroll
    for (int q = 0; q < 4; ++q) {
      float4 v = *(const float4*)(src + q * 4);
      Wt[j][cb + q * 4 + 0] = v.x; Wt[j][cb + q * 4 + 1] = v.y;
      Wt[j][cb + q * 4 + 2] = v.z; Wt[j][cb + q * 4 + 3] = v.w;
    }
  }
  __syncthreads();
  unsigned short pb[16];
#pragma unroll
  for (int r = 0; r < 16; ++r) {
    int rowl = (r & 3) + 8 * (r >> 2) + 4 * khalf;
    int coll = lane & 31;
    int il = wi * 32 + rowl, jl = wj * 32 + coll;
    float wd = W[(size_t)(i0 + il) * NROWS + (j0 + jl)];
    float ws = 0.5f * (wd + Wt[jl][il]);
    pb[r] = f2bf(acc[r] * ws);
  }
  __syncthreads();
#pragma unroll
  for (int r = 0; r < 16; ++r) {
    int rowl = (r & 3) + 8 * (r >> 2) + 4 * khalf;
    int coll = lane & 31;
    OutD[(wi * 32 + rowl) * 74 + wj * 32 + coll] = pb[r];
  }
  __syncthreads();
  const int row = t >> 3;
  const int seg = t & 7;
#pragma unroll
  for (int q = 0; q < 2; ++q) {
    int rr = row + q * 32;
    const unsigned int* pd = (const unsigned int*)(OutD + rr * 74 + seg * 8);
    union { u16x8 v; unsigned int u[4]; } dd;
#pragma unroll
    for (int k = 0; k < 4; ++k) dd.u[k] = pd[k];
    *(u16x8*)(PP + (size_t)(i0 + rr) * NROWS + j0 + seg * 8) = dd.v;
  }
}

// symmetric matvec partials over upper-triangle tiles
__global__ __launch_bounds__(256) void ppmv_sym(const unsigned short* __restrict__ PP,
                                                const float* __restrict__ coef_in,
                                                float* __restrict__ pE) {
  int bi, bj;
  tril_decode(blockIdx.x, bi, bj);
  const int i0 = bi * 64, j0 = bj * 64;
  const int t = threadIdx.x;

  __shared__ unsigned short tile[64][68];
  __shared__ float cj[64], ci[64], Tw[4][64], Dred[64];
  if (t < 64) cj[t] = coef_in[j0 + t];
  else if (t < 128) ci[t - 64] = coef_in[i0 + (t - 64)];
  {
    int r = t >> 2, c0 = (t & 3) * 16;
    const unsigned short* src = PP + (size_t)(i0 + r) * NROWS + j0 + c0;
    u16x8 v0 = *(const u16x8*)(src);
    u16x8 v1 = *(const u16x8*)(src + 8);
    *(u16x8*)&tile[r][c0] = v0;
    *(u16x8*)&tile[r][c0 + 8] = v1;
  }
  __syncthreads();
  {
    int r = t >> 2, c0 = (t & 3) * 16;
    float a = 0.f;
#pragma unroll
    for (int k = 0; k < 16; ++k) a += bf2f(tile[r][c0 + k]) * cj[c0 + k];
    a += __shfl_xor(a, 1);
    a += __shfl_xor(a, 2);
    if ((t & 3) == 0) Dred[r] = a;
  }
  {
    int c = t & 63, w = t >> 6;
    float a = 0.f;
#pragma unroll
    for (int k = 0; k < 16; ++k) a += bf2f(tile[w * 16 + k][c]) * ci[w * 16 + k];
    Tw[w][c] = a;
  }
  __syncthreads();
  if (t < 64) {
    pE[(size_t)bj * NROWS + i0 + t] = Dred[t];
    if (bi != bj) {
      float s = (Tw[0][t] + Tw[1][t]) + (Tw[2][t] + Tw[3][t]);
      pE[(size_t)bi * NROWS + j0 + t] = s;
    }
  }
}

// fold 128 slot-partials + unary -> lg; coef_out = 1-2*sigmoid(lg)
__global__ __launch_bounds__(128) void ppmv_reduce(const float* __restrict__ pE,
                                                   const float* __restrict__ unary,
                                                   float* __restrict__ coef_out,
                                                   float* __restrict__ lg_out) {
  int row = blockIdx.x * 128 + threadIdx.x;
  float acc = 0.f;
#pragma unroll 8
  for (int s = 0; s < 128; ++s) acc += pE[(size_t)s * NROWS + row];
  float lg = unary[row] + acc;
  coef_out[row] = 1.f - 2.f / (1.f + __expf(-lg));
  if (lg_out) lg_out[row] = lg;
}

extern "C" void kernel_launch(void* const* d_in, const int* in_sizes, int n_in,
                              void* d_out, int out_size, void* d_ws, size_t ws_size,
                              hipStream_t stream) {
  const float* x   = (const float*)d_in[0];
  const float* W   = (const float*)d_in[1];
  const float* W1  = (const float*)d_in[2];
  const float* g1  = (const float*)d_in[4];
  const float* be1 = (const float*)d_in[5];
  const float* W2  = (const float*)d_in[6];
  const float* g2  = (const float*)d_in[8];
  const float* be2 = (const float*)d_in[9];
  const float* fcw = (const float*)d_in[10];
  const float* fcb = (const float*)d_in[11];
  float* out = (float*)d_out;

  char* ws = (char*)d_ws;
  unsigned short* hraw = (unsigned short*)(ws + 0);          // 8 MB (pE aliases later)
  float* pE    = (float*)(ws + 0);                           // 4 MB, after hraw dead
  unsigned short* fraw = (unsigned short*)(ws + 8388608);    // 4 MB
  float* pS1   = (float*)(ws + 12582912);                    // 256 KB
  float* pQ1   = (float*)(ws + 12845056);                    // 256 KB
  float* pS2   = (float*)(ws + 13107200);                    // 128 KB
  float* pQ2   = (float*)(ws + 13238272);                    // 128 KB
  float2* ab1  = (float2*)(ws + 13369344);                   // 4 KB
  float2* ab2  = (float2*)(ws + 13373440);                   // 2 KB
  unsigned short* fnorm = (unsigned short*)(ws + 13375488);  // 4 MB
  float* unary = (float*)(ws + 17569792);
  float* coefA = (float*)(ws + 17602560);
  float* coefB = (float*)(ws + 17635328);
  unsigned short* hb  = (unsigned short*)(ws + 17668096);    // 8 MB
  unsigned short* xb  = (unsigned short*)(ws + 26056704);    // 2 MB
  unsigned short* w1b = (unsigned short*)(ws + 28153856);    // 128 KB
  unsigned short* w2b = (unsigned short*)(ws + 28284928);    // 256 KB
  unsigned short* PP  = (unsigned short*)(ws + 28547072);    // 128 MB
  if (ws_size < (size_t)162764800) return;

  // casts (one kernel)
  cast3<<<608, 256, 0, stream>>>(x, W1, W2, xb, w1b, w2b);
  // layer 1: hraw = x @ W1^T (bf16 out + fused col stats); BN; leaky -> hb
  gemm_bt_mfma_stats<<<dim3(128, 8), 256, 0, stream>>>(xb, w1b, hraw, pS1, pQ1, 512, 128);
  bn_finalize<<<2, 256, 0, stream>>>(pS1, pQ1, g1, be1, ab1, 512);
  bn_apply<<<2048, 256, 0, stream>>>(hraw, ab1, hb, 511);
  // layer 2: fraw = hb @ W2^T (bf16 out + fused col stats); BN+rowfn fused
  gemm_bt_mfma_stats<<<dim3(128, 4), 256, 0, stream>>>(hb, w2b, fraw, pS2, pQ2, 256, 512);
  bn_finalize<<<1, 256, 0, stream>>>(pS2, pQ2, g2, be2, ab2, 256);
  bn_rowfn<<<2048, 256, 0, stream>>>(fraw, ab2, fcw, fcb, fnorm, unary, coefA);
  // PP upper triangle (hraw dead; pE aliases it)
  ppbuild_sym<<<8256, 256, 0, stream>>>(fnorm, W, PP);
  // 10 symmetric-matvec iterations (2 kernels each; no grid.sync — it costs
  // ~125 us/sync on 8-XCD MI355X, measured round 8)
  float* cur = coefA; float* nxt = coefB;
  for (int it = 0; it < NITER; ++it) {
    ppmv_sym<<<8256, 256, 0, stream>>>(PP, cur, pE);
    ppmv_reduce<<<64, 128, 0, stream>>>(pE, unary, nxt, it == NITER - 1 ? out : nullptr);
    float* tmp = cur; cur = nxt; nxt = tmp;
  }
}

// Round 11
// 326.007 us; speedup vs baseline: 8.0276x; 1.0415x over previous
//
#include <hip/hip_runtime.h>
#include <hip/hip_bf16.h>

#define NROWS 8192
#define NITER 10

typedef __attribute__((ext_vector_type(8))) short bf16x8;
typedef __attribute__((ext_vector_type(8))) unsigned short u16x8;
typedef __attribute__((ext_vector_type(16))) float f32x16;

__device__ __forceinline__ float bf2f(unsigned short u) {
  union { float f; unsigned int i; } c; c.i = ((unsigned int)u) << 16; return c.f;
}
__device__ __forceinline__ unsigned short f2bf(float f) {
  unsigned int x = __float_as_uint(f);
  unsigned int r = (x + 0x7FFFu + ((x >> 16) & 1u)) >> 16;
  return (unsigned short)r;
}

// tril inversion, 128-wide grid (64x64 tiles) for ppbuild
#define TRIS(b) ((b) * (257 - (b)) / 2)
__device__ __forceinline__ void tril_decode(int L, int& bi, int& bj) {
  int b = (int)((257.0f - sqrtf((float)(66049 - 8 * L))) * 0.5f);
  if (b > 127) b = 127;
  if (b < 0) b = 0;
  while (b < 127 && TRIS(b + 1) <= L) ++b;
  while (b > 0 && TRIS(b) > L) --b;
  bi = b;
  bj = b + (L - TRIS(b));
}

// tril inversion, 64-wide grid (128x128 tiles) for ppmv
#define TRIS64(b) ((b) * (129 - (b)) / 2)
__device__ __forceinline__ void tril64_decode(int L, int& bi, int& bj) {
  int b = (int)((129.0f - sqrtf((float)(16641 - 8 * L))) * 0.5f);
  if (b > 63) b = 63;
  if (b < 0) b = 0;
  while (b < 63 && TRIS64(b + 1) <= L) ++b;
  while (b > 0 && TRIS64(b) > L) --b;
  bi = b;
  bj = b + (L - TRIS64(b));
}

// one kernel casting x, W1, W2 to bf16 (8 elems/thread)
__global__ __launch_bounds__(256) void cast3(const float* __restrict__ x,
                                             const float* __restrict__ W1,
                                             const float* __restrict__ W2,
                                             unsigned short* __restrict__ xb,
                                             unsigned short* __restrict__ w1b,
                                             unsigned short* __restrict__ w2b) {
  int idx = blockIdx.x * 256 + threadIdx.x;
  const float* src; unsigned short* dst; int l;
  if (idx < 131072) { src = x; dst = xb; l = idx; }
  else if (idx < 139264) { src = W1; dst = w1b; l = idx - 131072; }
  else if (idx < 155648) { src = W2; dst = w2b; l = idx - 139264; }
  else return;
  const float4* p = (const float4*)src + (size_t)l * 2;
  float4 a = p[0], b = p[1];
  u16x8 o;
  o[0] = f2bf(a.x); o[1] = f2bf(a.y); o[2] = f2bf(a.z); o[3] = f2bf(a.w);
  o[4] = f2bf(b.x); o[5] = f2bf(b.y); o[6] = f2bf(b.z); o[7] = f2bf(b.w);
  *(u16x8*)(dst + (size_t)l * 8) = o;
}

// C[M,NN] = A[M,K] @ B[NN,K]^T (bf16 in, bf16 out) + fused per-column
// partial BN stats (sum, sumsq) from the fp32 accumulators.
__global__ __launch_bounds__(256) void gemm_bt_mfma_stats(
    const unsigned short* __restrict__ A, const unsigned short* __restrict__ B,
    unsigned short* __restrict__ Cb, float* __restrict__ pS, float* __restrict__ pQ,
    int NN, int K) {
  __shared__ __align__(16) unsigned short Asw[4096];
  __shared__ __align__(16) unsigned short Bsw[4096];
  __shared__ float Sarr[4][64], Qarr[4][64];
  const int i0 = blockIdx.x * 64, j0 = blockIdx.y * 64;
  const int t = threadIdx.x;
  const int lane = t & 63;
  const int wv = t >> 6;
  const int wi = wv >> 1, wj = wv & 1;
  const int khalf = lane >> 5;

  f32x16 acc;
#pragma unroll
  for (int r = 0; r < 16; ++r) acc[r] = 0.f;

  const int lrow = t >> 2;
  const int lgp = (t & 3) * 2;
  const int arow = wi * 32 + (lane & 31);
  const int brow = wj * 32 + (lane & 31);
  const int nc = K >> 6;
#pragma unroll 1
  for (int c = 0; c < nc; ++c) {
    const unsigned short* sa = A + (size_t)(i0 + lrow) * K + c * 64 + lgp * 8;
    const unsigned short* sb = B + (size_t)(j0 + lrow) * K + c * 64 + lgp * 8;
    u16x8 va0 = *(const u16x8*)(sa);
    u16x8 va1 = *(const u16x8*)(sa + 8);
    u16x8 vb0 = *(const u16x8*)(sb);
    u16x8 vb1 = *(const u16x8*)(sb + 8);
    __syncthreads();
    int s0 = (lgp ^ (lrow & 7)) * 8;
    int s1 = ((lgp + 1) ^ (lrow & 7)) * 8;
    *(u16x8*)&Asw[lrow * 64 + s0] = va0;
    *(u16x8*)&Asw[lrow * 64 + s1] = va1;
    *(u16x8*)&Bsw[lrow * 64 + s0] = vb0;
    *(u16x8*)&Bsw[lrow * 64 + s1] = vb1;
    __syncthreads();
#pragma unroll
    for (int s = 0; s < 4; ++s) {
      int slot = s * 2 + khalf;
      bf16x8 a = *(const bf16x8*)&Asw[arow * 64 + ((slot ^ (arow & 7)) * 8)];
      bf16x8 b = *(const bf16x8*)&Bsw[brow * 64 + ((slot ^ (brow & 7)) * 8)];
      acc = __builtin_amdgcn_mfma_f32_32x32x16_bf16(a, b, acc, 0, 0, 0);
    }
  }
  // epilogue: bf16 store + per-lane column stats (16 rows of column coll)
  float s = 0.f, q = 0.f;
#pragma unroll
  for (int r = 0; r < 16; ++r) {
    int rowl = (r & 3) + 8 * (r >> 2) + 4 * khalf;
    int coll = lane & 31;
    float v = acc[r];
    s += v; q += v * v;
    Cb[(size_t)(i0 + wi * 32 + rowl) * NN + j0 + wj * 32 + coll] = f2bf(v);
  }
  Sarr[wv][lane] = s;
  Qarr[wv][lane] = q;
  __syncthreads();
  if (t < 64) {  // column c of block: fold 4 deterministic contributions
    int wjc = t >> 5, coll = t & 31;
    float st = (Sarr[wjc][coll] + Sarr[wjc][coll + 32]) +
               (Sarr[wjc + 2][coll] + Sarr[wjc + 2][coll + 32]);
    float qt = (Qarr[wjc][coll] + Qarr[wjc][coll + 32]) +
               (Qarr[wjc + 2][coll] + Qarr[wjc + 2][coll + 32]);
    pS[(size_t)blockIdx.x * NN + j0 + t] = st;
    pQ[(size_t)blockIdx.x * NN + j0 + t] = qt;
  }
}

// fold 128 row-block partial stats -> per-column scale/shift
__global__ void bn_finalize(const float* __restrict__ pS, const float* __restrict__ pQ,
                            const float* __restrict__ g, const float* __restrict__ be,
                            float2* __restrict__ ab, int C) {
  int c = blockIdx.x * 256 + threadIdx.x;
  if (c >= C) return;
  float s = 0.f, q = 0.f;
  for (int r = 0; r < 128; ++r) { s += pS[(size_t)r * C + c]; q += pQ[(size_t)r * C + c]; }
  const float invM = 1.f / 8192.f;
  float mu = s * invM;
  float var = q * invM - mu * mu;
  float rstd = rsqrtf(var + 1e-5f);
  float a = g[c] * rstd;
  ab[c] = make_float2(a, be[c] - mu * a);
}

// hb = leaky_relu(a*hraw + b), bf16 -> bf16, 8 elems/thread
__global__ __launch_bounds__(256) void bn_apply(const unsigned short* __restrict__ hraw,
                                                const float2* __restrict__ ab,
                                                unsigned short* __restrict__ hb,
                                                int Cmask) {
  size_t idx = (size_t)blockIdx.x * 256 + threadIdx.x;
  u16x8 v = *(const u16x8*)(hraw + idx * 8);
  int cb = (int)((idx * 8) & (size_t)Cmask);
  u16x8 o;
#pragma unroll
  for (int k = 0; k < 8; ++k) {
    float2 a = ab[cb + k];
    float r = a.x * bf2f(v[k]) + a.y;
    r = r >= 0.f ? r : 0.01f * r;
    o[k] = f2bf(r);
  }
  *(u16x8*)(hb + idx * 8) = o;
}

// fused: feats-BN + leaky + row norm + fc logit; writes fnorm bf16, unary, coef0
__global__ __launch_bounds__(256) void bn_rowfn(const unsigned short* __restrict__ fraw,
                                                const float2* __restrict__ ab,
                                                const float* __restrict__ fcw,
                                                const float* __restrict__ fcb,
                                                unsigned short* __restrict__ fnorm,
                                                float* __restrict__ unary,
                                                float* __restrict__ coef0) {
  const int lane = threadIdx.x & 63;
  const int row = blockIdx.x * 4 + (threadIdx.x >> 6);
  ushort4 v4 = *(const ushort4*)(fraw + (size_t)row * 256 + lane * 4);
  float4 w = *(const float4*)(fcw + lane * 4);
  int c = lane * 4;
  float2 a0 = ab[c], a1 = ab[c + 1], a2 = ab[c + 2], a3 = ab[c + 3];
  float f0 = a0.x * bf2f(v4.x) + a0.y; f0 = f0 >= 0.f ? f0 : 0.01f * f0;
  float f1 = a1.x * bf2f(v4.y) + a1.y; f1 = f1 >= 0.f ? f1 : 0.01f * f1;
  float f2 = a2.x * bf2f(v4.z) + a2.y; f2 = f2 >= 0.f ? f2 : 0.01f * f2;
  float f3 = a3.x * bf2f(v4.w) + a3.y; f3 = f3 >= 0.f ? f3 : 0.01f * f3;
  float ssq = f0 * f0 + f1 * f1 + f2 * f2 + f3 * f3;
  float dot = f0 * w.x + f1 * w.y + f2 * w.z + f3 * w.w;
#pragma unroll
  for (int o = 32; o; o >>= 1) { ssq += __shfl_xor(ssq, o); dot += __shfl_xor(dot, o); }
  float rfn = rsqrtf(ssq);
  *(ushort4*)(fnorm + (size_t)row * 256 + lane * 4) =
      make_ushort4(f2bf(f0 * rfn), f2bf(f1 * rfn), f2bf(f2 * rfn), f2bf(f3 * rfn));
  if (lane == 0) {
    float lg = dot + fcb[0];
    unary[row] = lg;
    coef0[row] = 1.f - 2.f / (1.f + __expf(-lg));
  }
}

// PP[i,j] = (fnorm_i . fnorm_j) * 0.5*(W[i,j]+W[j,i]); upper-triangle only.
__global__ __launch_bounds__(256) void ppbuild_sym(const unsigned short* __restrict__ fnorm,
                                                   const float* __restrict__ W,
                                                   unsigned short* __restrict__ PP) {
  int bi, bj;
  tril_decode(blockIdx.x, bi, bj);
  const int i0 = bi * 64, j0 = bj * 64;

  __shared__ __align__(16) unsigned char shm[18944];
  unsigned short* Asw = (unsigned short*)shm;
  unsigned short* Bsw = (unsigned short*)shm + 4736;
  float (*Wt)[68] = (float(*)[68])shm;
  unsigned short* OutD = (unsigned short*)shm;

  const int t = threadIdx.x;
  const int lane = t & 63;
  const int wv = t >> 6;
  const int wi = wv >> 1, wj = wv & 1;
  const int khalf = lane >> 5;

  f32x16 acc;
#pragma unroll
  for (int r = 0; r < 16; ++r) acc[r] = 0.f;

  const int lrow = t >> 2;
  const int lgp = (t & 3) * 2;
  const int arow = wi * 32 + (lane & 31);
  const int brow = wj * 32 + (lane & 31);
#pragma unroll 1
  for (int c = 0; c < 4; ++c) {
    const unsigned short* sa = fnorm + (size_t)(i0 + lrow) * 256 + c * 64 + lgp * 8;
    const unsigned short* sb = fnorm + (size_t)(j0 + lrow) * 256 + c * 64 + lgp * 8;
    u16x8 va0 = *(const u16x8*)(sa);
    u16x8 va1 = *(const u16x8*)(sa + 8);
    u16x8 vb0 = *(const u16x8*)(sb);
    u16x8 vb1 = *(const u16x8*)(sb + 8);
    __syncthreads();
    int s0 = (lgp ^ (lrow & 7)) * 8;
    int s1 = ((lgp + 1) ^ (lrow & 7)) * 8;
    *(u16x8*)&Asw[lrow * 64 + s0] = va0;
    *(u16x8*)&Asw[lrow * 64 + s1] = va1;
    *(u16x8*)&Bsw[lrow * 64 + s0] = vb0;
    *(u16x8*)&Bsw[lrow * 64 + s1] = vb1;
    __syncthreads();
#pragma unroll
    for (int s = 0; s < 4; ++s) {
      int slot = s * 2 + khalf;
      bf16x8 a = *(const bf16x8*)&Asw[arow * 64 + ((slot ^ (arow & 7)) * 8)];
      bf16x8 b = *(const bf16x8*)&Bsw[brow * 64 + ((slot ^ (brow & 7)) * 8)];
      acc = __builtin_amdgcn_mfma_f32_32x32x16_bf16(a, b, acc, 0, 0, 0);
    }
  }

  __syncthreads();
  {
    const int j = t >> 2, cb = (t & 3) * 16;
    const float* src = W + (size_t)(j0 + j) * NROWS + i0 + cb;
#pragma unroll
    for (int q = 0; q < 4; ++q) {
      float4 v = *(const float4*)(src + q * 4);
      Wt[j][cb + q * 4 + 0] = v.x; Wt[j][cb + q * 4 + 1] = v.y;
      Wt[j][cb + q * 4 + 2] = v.z; Wt[j][cb + q * 4 + 3] = v.w;
    }
  }
  __syncthreads();
  unsigned short pb[16];
#pragma unroll
  for (int r = 0; r < 16; ++r) {
    int rowl = (r & 3) + 8 * (r >> 2) + 4 * khalf;
    int coll = lane & 31;
    int il = wi * 32 + rowl, jl = wj * 32 + coll;
    float wd = W[(size_t)(i0 + il) * NROWS + (j0 + jl)];
    float ws = 0.5f * (wd + Wt[jl][il]);
    pb[r] = f2bf(acc[r] * ws);
  }
  __syncthreads();
#pragma unroll
  for (int r = 0; r < 16; ++r) {
    int rowl = (r & 3) + 8 * (r >> 2) + 4 * khalf;
    int coll = lane & 31;
    OutD[(wi * 32 + rowl) * 74 + wj * 32 + coll] = pb[r];
  }
  __syncthreads();
  const int row = t >> 3;
  const int seg = t & 7;
#pragma unroll
  for (int q = 0; q < 2; ++q) {
    int rr = row + q * 32;
    const unsigned int* pd = (const unsigned int*)(OutD + rr * 74 + seg * 8);
    union { u16x8 v; unsigned int u[4]; } dd;
#pragma unroll
    for (int k = 0; k < 4; ++k) dd.u[k] = pd[k];
    *(u16x8*)(PP + (size_t)(i0 + rr) * NROWS + j0 + seg * 8) = dd.v;
  }
}

// symmetric matvec partials, 128x128 tiles over a 64-block triangular grid.
// Tile (bi,bj): D[r] = sum_c PP[r][c]*cj[c] -> pE[bj][i0+r]
//              T[c] = sum_r PP[r][c]*ci[r] -> pE[bi][j0+c]  (bi!=bj)
__global__ __launch_bounds__(256) void ppmv_sym(const unsigned short* __restrict__ PP,
                                                const float* __restrict__ coef_in,
                                                float* __restrict__ pE) {
  int bi, bj;
  tril64_decode(blockIdx.x, bi, bj);
  const int i0 = bi * 128, j0 = bj * 128;
  const int t = threadIdx.x;

  __shared__ __align__(16) unsigned short tile[128][132];  // 33792 B
  __shared__ float cj[128], ci[128];
  __shared__ float Tw[8][128];
  __shared__ float Dred[128];

  if (t < 128) cj[t] = coef_in[j0 + t];
  else ci[t - 128] = coef_in[i0 + (t - 128)];
  {
    const int r = t >> 1, h = (t & 1) * 64;
    const unsigned short* src = PP + (size_t)(i0 + r) * NROWS + j0 + h;
#pragma unroll
    for (int q = 0; q < 8; ++q)
      *(u16x8*)&tile[r][h + q * 8] = *(const u16x8*)(src + q * 8);
  }
  __syncthreads();
  // row sums: thread owns half a row (64 cols), vectorized LDS reads
  {
    const int r = t >> 1, h = (t & 1) * 64;
    float a = 0.f;
#pragma unroll
    for (int q = 0; q < 8; ++q) {
      u16x8 v = *(const u16x8*)&tile[r][h + q * 8];
      float4 c0 = *(const float4*)&cj[h + q * 8];
      float4 c1 = *(const float4*)&cj[h + q * 8 + 4];
      a += bf2f(v[0]) * c0.x + bf2f(v[1]) * c0.y + bf2f(v[2]) * c0.z + bf2f(v[3]) * c0.w;
      a += bf2f(v[4]) * c1.x + bf2f(v[5]) * c1.y + bf2f(v[6]) * c1.z + bf2f(v[7]) * c1.w;
    }
    a += __shfl_xor(a, 1);
    if ((t & 1) == 0) Dred[r] = a;
  }
  // col sums: thread owns 4 cols x 16 rows (ushort4 LDS reads), 8 row-groups
  {
    const int c4 = (t & 31) * 4, rg = t >> 5;
    float a0 = 0.f, a1 = 0.f, a2 = 0.f, a3 = 0.f;
#pragma unroll
    for (int k = 0; k < 16; ++k) {
      int row = rg * 16 + k;
      ushort4 v = *(const ushort4*)&tile[row][c4];
      float s = ci[row];
      a0 += bf2f(v.x) * s; a1 += bf2f(v.y) * s;
      a2 += bf2f(v.z) * s; a3 += bf2f(v.w) * s;
    }
    Tw[rg][c4] = a0; Tw[rg][c4 + 1] = a1;
    Tw[rg][c4 + 2] = a2; Tw[rg][c4 + 3] = a3;
  }
  __syncthreads();
  if (t < 128) {
    pE[(size_t)bj * NROWS + i0 + t] = Dred[t];
    if (bi != bj) {
      float s = ((Tw[0][t] + Tw[1][t]) + (Tw[2][t] + Tw[3][t])) +
                ((Tw[4][t] + Tw[5][t]) + (Tw[6][t] + Tw[7][t]));
      pE[(size_t)bi * NROWS + j0 + t] = s;
    }
  }
}

// fold 64 slot-partials + unary -> lg; coef_out = 1-2*sigmoid(lg)
__global__ __launch_bounds__(256) void ppmv_reduce(const float* __restrict__ pE,
                                                   const float* __restrict__ unary,
                                                   float* __restrict__ coef_out,
                                                   float* __restrict__ lg_out) {
  int row = blockIdx.x * 256 + threadIdx.x;
  float acc = 0.f;
#pragma unroll 8
  for (int s = 0; s < 64; ++s) acc += pE[(size_t)s * NROWS + row];
  float lg = unary[row] + acc;
  coef_out[row] = 1.f - 2.f / (1.f + __expf(-lg));
  if (lg_out) lg_out[row] = lg;
}

extern "C" void kernel_launch(void* const* d_in, const int* in_sizes, int n_in,
                              void* d_out, int out_size, void* d_ws, size_t ws_size,
                              hipStream_t stream) {
  const float* x   = (const float*)d_in[0];
  const float* W   = (const float*)d_in[1];
  const float* W1  = (const float*)d_in[2];
  const float* g1  = (const float*)d_in[4];
  const float* be1 = (const float*)d_in[5];
  const float* W2  = (const float*)d_in[6];
  const float* g2  = (const float*)d_in[8];
  const float* be2 = (const float*)d_in[9];
  const float* fcw = (const float*)d_in[10];
  const float* fcb = (const float*)d_in[11];
  float* out = (float*)d_out;

  char* ws = (char*)d_ws;
  unsigned short* hraw = (unsigned short*)(ws + 0);          // 8 MB (pE aliases later)
  float* pE    = (float*)(ws + 0);                           // 2 MB, after hraw dead
  unsigned short* fraw = (unsigned short*)(ws + 8388608);    // 4 MB
  float* pS1   = (float*)(ws + 12582912);                    // 256 KB
  float* pQ1   = (float*)(ws + 12845056);                    // 256 KB
  float* pS2   = (float*)(ws + 13107200);                    // 128 KB
  float* pQ2   = (float*)(ws + 13238272);                    // 128 KB
  float2* ab1  = (float2*)(ws + 13369344);                   // 4 KB
  float2* ab2  = (float2*)(ws + 13373440);                   // 2 KB
  unsigned short* fnorm = (unsigned short*)(ws + 13375488);  // 4 MB
  float* unary = (float*)(ws + 17569792);
  float* coefA = (float*)(ws + 17602560);
  float* coefB = (float*)(ws + 17635328);
  unsigned short* hb  = (unsigned short*)(ws + 17668096);    // 8 MB
  unsigned short* xb  = (unsigned short*)(ws + 26056704);    // 2 MB
  unsigned short* w1b = (unsigned short*)(ws + 28153856);    // 128 KB
  unsigned short* w2b = (unsigned short*)(ws + 28284928);    // 256 KB
  unsigned short* PP  = (unsigned short*)(ws + 28547072);    // 128 MB
  if (ws_size < (size_t)162764800) return;

  // casts (one kernel)
  cast3<<<608, 256, 0, stream>>>(x, W1, W2, xb, w1b, w2b);
  // layer 1: hraw = x @ W1^T (bf16 out + fused col stats); BN; leaky -> hb
  gemm_bt_mfma_stats<<<dim3(128, 8), 256, 0, stream>>>(xb, w1b, hraw, pS1, pQ1, 512, 128);
  bn_finalize<<<2, 256, 0, stream>>>(pS1, pQ1, g1, be1, ab1, 512);
  bn_apply<<<2048, 256, 0, stream>>>(hraw, ab1, hb, 511);
  // layer 2: fraw = hb @ W2^T (bf16 out + fused col stats); BN+rowfn fused
  gemm_bt_mfma_stats<<<dim3(128, 4), 256, 0, stream>>>(hb, w2b, fraw, pS2, pQ2, 256, 512);
  bn_finalize<<<1, 256, 0, stream>>>(pS2, pQ2, g2, be2, ab2, 256);
  bn_rowfn<<<2048, 256, 0, stream>>>(fraw, ab2, fcw, fcb, fnorm, unary, coefA);
  // PP upper triangle (hraw dead; pE aliases it)
  ppbuild_sym<<<8256, 256, 0, stream>>>(fnorm, W, PP);
  // 10 symmetric-matvec iterations, 128x128 tiles (2080 blocks)
  float* cur = coefA; float* nxt = coefB;
  for (int it = 0; it < NITER; ++it) {
    ppmv_sym<<<2080, 256, 0, stream>>>(PP, cur, pE);
    ppmv_reduce<<<32, 256, 0, stream>>>(pE, unary, nxt, it == NITER - 1 ? out : nullptr);
    float* tmp = cur; cur = nxt; nxt = tmp;
  }
}